// Round 3
// baseline (79.863 us; speedup 1.0000x reference)
//
#include <hip/hip_runtime.h>
#include <math.h>

#define EPS 1e-6f

constexpr int BLOCK = 256;
constexpr int GRID  = 2048;

typedef int   vi4 __attribute__((ext_vector_type(4)));
typedef float vf4 __attribute__((ext_vector_type(4)));

// Stage 0: pad x [V,3] -> xp [V] float4 (w unused) so each vertex gather is
// a single global_load_dwordx4 instead of 3 scalar dwords.
__global__ __launch_bounds__(BLOCK) void pad_vertices(
    const float* __restrict__ x,
    vf4* __restrict__ xp,
    int nverts)
{
    int v = blockIdx.x * BLOCK + threadIdx.x;
    if (v < nverts) {
        const float* p = x + 3 * v;
        vf4 t = {p[0], p[1], p[2], 0.f};
        xp[v] = t;
    }
}

// Stage 1: per-block partial sums of k*dl*dl over all springs.
__global__ __launch_bounds__(BLOCK) void spring_energy_partial(
    const vf4*   __restrict__ xp,
    const float* __restrict__ l0,
    const float* __restrict__ k,
    const int*   __restrict__ idx,
    float* __restrict__ partials,
    int nsprings)
{
    const int tid      = blockIdx.x * BLOCK + threadIdx.x;
    const int nthreads = GRID * BLOCK;
    const int nquads   = nsprings >> 2;   // 4 springs per iteration

    float acc = 0.f;
    for (int q = tid; q < nquads; q += nthreads) {
        const int s = q << 2;
        // streaming loads: nontemporal so they don't evict xp from L2
        vi4 ia  = __builtin_nontemporal_load(reinterpret_cast<const vi4*>(idx + 2 * s));
        vi4 ib  = __builtin_nontemporal_load(reinterpret_cast<const vi4*>(idx + 2 * s) + 1);
        vf4 l0v = __builtin_nontemporal_load(reinterpret_cast<const vf4*>(l0 + s));
        vf4 kv  = __builtin_nontemporal_load(reinterpret_cast<const vf4*>(k + s));

        // 8 independent float4 gathers -> good memory-level parallelism
        vf4 a0 = xp[ia.x], b0 = xp[ia.y];
        vf4 a1 = xp[ia.z], b1 = xp[ia.w];
        vf4 a2 = xp[ib.x], b2 = xp[ib.y];
        vf4 a3 = xp[ib.z], b3 = xp[ib.w];

        float dx, dy, dz, qd, l, dl;

        dx = a0.x - b0.x; dy = a0.y - b0.y; dz = a0.z - b0.z;
        qd = dx*dx + dy*dy + dz*dz;
        l  = sqrtf(qd + EPS); dl = l - l0v.x;
        acc = fmaf(kv.x * dl, dl, acc);

        dx = a1.x - b1.x; dy = a1.y - b1.y; dz = a1.z - b1.z;
        qd = dx*dx + dy*dy + dz*dz;
        l  = sqrtf(qd + EPS); dl = l - l0v.y;
        acc = fmaf(kv.y * dl, dl, acc);

        dx = a2.x - b2.x; dy = a2.y - b2.y; dz = a2.z - b2.z;
        qd = dx*dx + dy*dy + dz*dz;
        l  = sqrtf(qd + EPS); dl = l - l0v.z;
        acc = fmaf(kv.z * dl, dl, acc);

        dx = a3.x - b3.x; dy = a3.y - b3.y; dz = a3.z - b3.z;
        qd = dx*dx + dy*dy + dz*dz;
        l  = sqrtf(qd + EPS); dl = l - l0v.w;
        acc = fmaf(kv.w * dl, dl, acc);
    }

    // scalar tail (nsprings % 4), handled by block 0 only
    if (blockIdx.x == 0) {
        for (int s = (nquads << 2) + threadIdx.x; s < nsprings; s += BLOCK) {
            int i1 = idx[2 * s], i2 = idx[2 * s + 1];
            vf4 a = xp[i1], b = xp[i2];
            float dx = a.x - b.x, dy = a.y - b.y, dz = a.z - b.z;
            float l  = sqrtf(dx*dx + dy*dy + dz*dz + EPS);
            float dl = l - l0[s];
            acc = fmaf(k[s] * dl, dl, acc);
        }
    }

    // wave (64-lane) reduction
    #pragma unroll
    for (int off = 32; off > 0; off >>= 1)
        acc += __shfl_down(acc, off, 64);

    __shared__ float wsum[BLOCK / 64];
    const int lane = threadIdx.x & 63;
    const int wid  = threadIdx.x >> 6;
    if (lane == 0) wsum[wid] = acc;
    __syncthreads();
    if (threadIdx.x == 0)
        partials[blockIdx.x] = wsum[0] + wsum[1] + wsum[2] + wsum[3];
}

// Stage 2: deterministic final reduction of GRID partials -> scalar energy.
__global__ __launch_bounds__(BLOCK) void spring_energy_final(
    const float* __restrict__ partials,
    float* __restrict__ out)
{
    float acc = 0.f;
    for (int i = threadIdx.x; i < GRID; i += BLOCK)
        acc += partials[i];

    #pragma unroll
    for (int off = 32; off > 0; off >>= 1)
        acc += __shfl_down(acc, off, 64);

    __shared__ float wsum[BLOCK / 64];
    const int lane = threadIdx.x & 63;
    const int wid  = threadIdx.x >> 6;
    if (lane == 0) wsum[wid] = acc;
    __syncthreads();
    if (threadIdx.x == 0)
        out[0] = 0.5f * (wsum[0] + wsum[1] + wsum[2] + wsum[3]);
}

extern "C" void kernel_launch(void* const* d_in, const int* in_sizes, int n_in,
                              void* d_out, int out_size, void* d_ws, size_t ws_size,
                              hipStream_t stream) {
    // setup_inputs() order: x [V,3] f32, l0 [E] f32, k [E] f32, indices [E,2] i32
    const float* x   = (const float*)d_in[0];
    const float* l0  = (const float*)d_in[1];
    const float* k   = (const float*)d_in[2];
    const int*   idx = (const int*)  d_in[3];
    float* out       = (float*)d_out;

    const int nverts   = in_sizes[0] / 3;   // V = 100,000
    const int nsprings = in_sizes[1];       // E = 6,400,000

    // d_ws layout: [0, nverts*16) padded vertices, then GRID floats of partials
    vf4*   xp       = (vf4*)d_ws;
    float* partials = (float*)((char*)d_ws + (size_t)nverts * sizeof(vf4));

    pad_vertices<<<(nverts + BLOCK - 1) / BLOCK, BLOCK, 0, stream>>>(x, xp, nverts);
    spring_energy_partial<<<GRID, BLOCK, 0, stream>>>(xp, l0, k, idx, partials, nsprings);
    spring_energy_final<<<1, BLOCK, 0, stream>>>(partials, out);
}